// Round 1
// baseline (2124.207 us; speedup 1.0000x reference)
//
#include <hip/hip_runtime.h>
#include <math.h>

// Problem constants
#define CCH 128
#define HH 64
#define WW 64
#define NSAMP 16
#define KPER (CCH*HH*WW)   // 524288 elements per sample
#define SHD 17             // shifts per dim (2*8+1)
#define NSHIFT (SHD*SHD)   // 289

// Workspace layout (in floats):
// [0,16)        sat sumsq per sample
// [16,32)       grd sumsq per sample
// [32, 32+73984)        raw corr accumulator, index [(m*16+n)*289 + s]   (zero-init)
// [74016, 74016+65536)  energy[m,y,x] = sum_c sat^2
// [139552, 139552+4624) scale[m,s] = 1/max(sqrt(window_energy),eps)
#define OFF_NORM   0
#define OFF_RAW    32
#define OFF_ENERGY 74016
#define OFF_SCALE  139552
#define ZERO_BYTES ((32 + 16*16*NSHIFT) * 4)   // 296064

#define KC 8   // K-chunks for corr kernel (split-K via atomics)

// ---------------- K1: per-sample sum of squares ----------------
__global__ void k_sumsq(const float* __restrict__ sat,
                        const float* __restrict__ grd,
                        float* __restrict__ ws) {
    const int PARTS = 8;
    int b    = blockIdx.x;          // 32*PARTS blocks
    int samp = b / PARTS;           // 0..31  (0-15 sat, 16-31 grd)
    int part = b % PARTS;
    const float* src = (samp < NSAMP) ? (sat + (size_t)samp * KPER)
                                      : (grd + (size_t)(samp - NSAMP) * KPER);
    const int chunk = KPER / PARTS; // 65536
    float s = 0.f;
    for (int k = part * chunk + threadIdx.x; k < (part + 1) * chunk; k += blockDim.x) {
        float v = src[k];
        s += v * v;
    }
    #pragma unroll
    for (int off = 32; off; off >>= 1) s += __shfl_xor(s, off);
    __shared__ float red[4];
    int lane = threadIdx.x & 63, wv = threadIdx.x >> 6;
    if (lane == 0) red[wv] = s;
    __syncthreads();
    if (threadIdx.x == 0) {
        float t = red[0] + red[1] + red[2] + red[3];
        atomicAdd(&ws[OFF_NORM + samp], t);
    }
}

// ---------------- K2: channel-summed energy of sat ----------------
__global__ void k_energy(const float* __restrict__ sat, float* __restrict__ ws) {
    float* energy = ws + OFF_ENERGY;
    int m = blockIdx.x >> 6;   // grid = 16*64 blocks, 64 threads
    int y = blockIdx.x & 63;
    int x = threadIdx.x;
    const float* p = sat + (size_t)m * KPER + y * WW + x;
    float s = 0.f;
    #pragma unroll 4
    for (int c = 0; c < CCH; ++c) {
        float v = p[(size_t)c * HH * WW];
        s += v * v;
    }
    energy[(m * HH + y) * WW + x] = s;
}

// ---------------- K3: windowed energy -> scale ----------------
__global__ void k_scale(float* __restrict__ ws) {
    const float* energy = ws + OFF_ENERGY;
    float* scale = ws + OFF_SCALE;
    int b = blockIdx.x;            // 16*289 blocks
    int m = b / NSHIFT, s = b % NSHIFT;
    int i = s / SHD, j = s % SHD;
    int y0 = max(0, i - 8), y1 = min(HH, i + 56);
    int x0 = max(0, j - 8), x1 = min(WW, j + 56);
    int ny = y1 - y0, nx = x1 - x0, tot = ny * nx;
    float acc = 0.f;
    for (int idx = threadIdx.x; idx < tot; idx += blockDim.x) {
        int yy = y0 + idx / nx, xx = x0 + idx % nx;
        acc += energy[(m * HH + yy) * WW + xx];
    }
    #pragma unroll
    for (int off = 32; off; off >>= 1) acc += __shfl_xor(acc, off);
    __shared__ float red[4];
    int lane = threadIdx.x & 63, wv = threadIdx.x >> 6;
    if (lane == 0) red[wv] = acc;
    __syncthreads();
    if (threadIdx.x == 0) {
        float t = red[0] + red[1] + red[2] + red[3];
        scale[b] = 1.f / fmaxf(sqrtf(t), 1e-12f);
    }
}

// ---------------- K4: the big cross-correlation ----------------
// Block = 256 threads = 4 waves. Wave w: (mh,nh)=(w&1,w>>1) -> 8x8 (m,n) tile.
// Lane l = w-coordinate. Each block: one shift s, one K-chunk of rows (c,h).
__global__ __launch_bounds__(256) void k_corr(const float* __restrict__ sat,
                                              const float* __restrict__ grd,
                                              float* __restrict__ ws) {
    float* raw = ws + OFF_RAW;
    int s     = blockIdx.x % NSHIFT;
    int chunk = blockIdx.x / NSHIFT;
    int i = s / SHD, j = s % SHD;
    int dy = i - 8, dx = j - 8;
    int wv = threadIdx.x >> 6;
    int l  = threadIdx.x & 63;
    int mh = wv & 1, nh = wv >> 1;
    const float* satm = sat + (size_t)(mh * 8) * KPER;
    const float* grdn = grd + (size_t)(nh * 8) * KPER;

    float acc[64];
    #pragma unroll
    for (int a = 0; a < 64; ++a) acc[a] = 0.f;

    const int ROWS = CCH * HH;  // 8192 (c,h) rows
    int r0 = chunk * (ROWS / KC), r1 = r0 + ROWS / KC;
    int xs = l + dx;
    bool vx = (unsigned)xs < (unsigned)WW;

    for (int r = r0; r < r1; ++r) {
        int h = r & (HH - 1);
        int y = h + dy;
        if ((unsigned)y >= (unsigned)HH) continue;   // uniform branch
        size_t goff = (size_t)r * WW + l;
        size_t soff = (size_t)(r + dy) * WW + xs;    // (c*64 + y)*64 + xs
        float gv[8], sv[8];
        #pragma unroll
        for (int q = 0; q < 8; ++q) gv[q] = grdn[(size_t)q * KPER + goff];
        #pragma unroll
        for (int q = 0; q < 8; ++q) sv[q] = vx ? satm[(size_t)q * KPER + soff] : 0.f;
        #pragma unroll
        for (int mi = 0; mi < 8; ++mi)
            #pragma unroll
            for (int ni = 0; ni < 8; ++ni)
                acc[mi * 8 + ni] += sv[mi] * gv[ni];
    }

    // butterfly-reduce each accumulator over the 64 lanes; lane a commits acc[a]
    #pragma unroll
    for (int a = 0; a < 64; ++a) {
        float v = acc[a];
        #pragma unroll
        for (int off = 32; off; off >>= 1) v += __shfl_xor(v, off);
        if (l == a) {
            int m = mh * 8 + (a >> 3);
            int n = nh * 8 + (a & 7);
            atomicAdd(&raw[(m * 16 + n) * NSHIFT + s], v);
        }
    }
}

// ---------------- K5: epilogue -> 3 scalars ----------------
__global__ void k_final(const float* __restrict__ ws, float* __restrict__ out) {
    const float* raw   = ws + OFF_RAW;
    const float* scale = ws + OFF_SCALE;
    const float* norms = ws + OFF_NORM;
    __shared__ float dist_s[256];
    __shared__ float pos_s[16];
    __shared__ float red[256];
    __shared__ float minv[16];
    int t = threadIdx.x;          // 256 threads, t = m*16 + n
    int m = t >> 4, n = t & 15;

    float best = -1e30f;
    const float* rp = raw + (size_t)t * NSHIFT;
    const float* sp = scale + m * NSHIFT;
    for (int s = 0; s < NSHIFT; ++s) best = fmaxf(best, rp[s] * sp[s]);
    float Ng  = sqrtf(norms[16 + n]);
    float sim = best / fmaxf(Ng, 1e-12f);
    float d   = 2.f - 2.f * sim;
    dist_s[t] = d;
    if (m == n) pos_s[m] = d;
    __syncthreads();

    float x1 = (pos_s[n] - d) * 10.f;   // g2s: pos[None,:] - dist
    float x2 = (pos_s[m] - d) * 10.f;   // s2g: pos[:,None] - dist
    float sp1 = x1 > 20.f ? x1 : log1pf(expf(x1));
    float sp2 = x2 > 20.f ? x2 : log1pf(expf(x2));
    red[t] = sp1 + sp2;
    __syncthreads();
    for (int off = 128; off; off >>= 1) {
        if (t < off) red[t] += red[t + off];
        __syncthreads();
    }
    if (t < 16) {
        float mv = 1e30f;
        for (int nn = 0; nn < 16; ++nn) mv = fminf(mv, dist_s[t * 16 + nn]);
        minv[t] = mv;
    }
    __syncthreads();
    if (t == 0) {
        float psum = 0.f, msum = 0.f;
        for (int q = 0; q < 16; ++q) { psum += pos_s[q]; msum += minv[q]; }
        // 10 * ((sum1/240 + sum2/240)/2) = total/48
        out[0] = red[0] / 48.f;
        out[1] = psum / 16.f;
        out[2] = msum / 16.f;
    }
}

extern "C" void kernel_launch(void* const* d_in, const int* in_sizes, int n_in,
                              void* d_out, int out_size, void* d_ws, size_t ws_size,
                              hipStream_t stream) {
    const float* sat = (const float*)d_in[0];
    const float* grd = (const float*)d_in[1];
    float* out = (float*)d_out;
    float* ws  = (float*)d_ws;

    // zero the accumulated regions (norms + raw corr)
    hipMemsetAsync(d_ws, 0, ZERO_BYTES, stream);

    k_sumsq <<<32 * 8,        256, 0, stream>>>(sat, grd, ws);
    k_energy<<<NSAMP * HH,     64, 0, stream>>>(sat, ws);
    k_scale <<<NSAMP * NSHIFT, 256, 0, stream>>>(ws);
    k_corr  <<<NSHIFT * KC,    256, 0, stream>>>(sat, grd, ws);
    k_final <<<1,              256, 0, stream>>>(ws, out);
}

// Round 2
// 514.578 us; speedup vs baseline: 4.1281x; 4.1281x over previous
//
#include <hip/hip_runtime.h>
#include <math.h>

#define CCH 128
#define HH 64
#define WW 64
#define NSAMP 16
#define SHD 17
#define NSHIFT (SHD*SHD)   // 289

// ---- workspace layout (floats unless noted) ----
#define OFF_RAW    0                         // 16*16*289 = 73984 floats
#define OFF_NORM   73984                     // 16 floats (grd sumsq)
#define OFF_ENERGY 74000                     // 16*64*64 floats
#define OFF_SCALE  139536                    // 16*289 floats
#define OFF_SATB_B 576640                    // bytes; bf16 satb, 16 MB
#define TENSOR_U16 8388608u                  // ushorts per tensor (16*128*64*64)
#define ZERO_BYTES 296000                    // raw + norm

typedef __bf16 bf16x8 __attribute__((ext_vector_type(8)));
typedef float floatx4 __attribute__((ext_vector_type(4)));
typedef unsigned short ushort8 __attribute__((ext_vector_type(8)));

#define AS1 __attribute__((address_space(1)))
#define AS3 __attribute__((address_space(3)))

__device__ inline unsigned short f2bf(float f) {
    unsigned x = __float_as_uint(f);
    unsigned r = x + 0x7FFFu + ((x >> 16) & 1u);   // RNE
    return (unsigned short)(r >> 16);
}

// ---------------- K1: convert + transpose + norms/energy ----------------
// grid: 2 tensors * 16 samples * 64 h = 2048 blocks, 256 threads
__global__ __launch_bounds__(256) void k_prep(const float* __restrict__ sat,
                                              const float* __restrict__ grd,
                                              float* __restrict__ ws) {
    __shared__ unsigned short tile[64 * 128];   // [w][16 chunks xor-swizzled][8] = 16KB
    __shared__ float ered[4][64];
    int b = blockIdx.x;
    int tensor = b >> 10, n = (b >> 6) & 15, h = b & 63;
    const float* src = tensor ? grd : sat;
    unsigned short* dst = (unsigned short*)((char*)ws + OFF_SATB_B) + (size_t)tensor * TENSOR_U16;
    int t = threadIdx.x;
    int w = t & 63, cg4 = t >> 6;

    float esum = 0.f;
    #pragma unroll
    for (int it = 0; it < 4; ++it) {
        int cg = it * 4 + cg4;      // c-group (8 channels)
        int cb = cg * 8;
        ushort8 pack;
        #pragma unroll
        for (int j = 0; j < 8; ++j) {
            float v = src[(((size_t)n * CCH + cb + j) * HH + h) * WW + w];
            esum = fmaf(v, v, esum);
            pack[j] = f2bf(v);
        }
        int chunk = cg ^ (w & 15);
        *(ushort8*)&tile[(w * 16 + chunk) * 8] = pack;
    }
    ered[cg4][w] = esum;
    __syncthreads();
    if (t < 64) {
        float e = ered[0][t] + ered[1][t] + ered[2][t] + ered[3][t];
        if (tensor == 0) {
            ws[OFF_ENERGY + ((size_t)n * HH + h) * WW + t] = e;   // energy[m][h][w]
        } else {
            #pragma unroll
            for (int off = 32; off; off >>= 1) e += __shfl_xor(e, off);
            if (t == 0) atomicAdd(&ws[OFF_NORM + n], e);
        }
    }
    // transposed write: dst[((h*64+w)*16 + n)*128 + c]
    int wq = t >> 2, q = t & 3;
    size_t obase = ((size_t)(h * 64 + wq) * 16 + n) * 128;
    #pragma unroll
    for (int c4 = 0; c4 < 4; ++c4) {
        int cg = q * 4 + c4;
        int chunk = cg ^ (wq & 15);
        ushort8 val = *(ushort8*)&tile[(wq * 16 + chunk) * 8];
        *(ushort8*)&dst[obase + cg * 8] = val;
    }
}

// ---------------- K2: windowed energy -> scale ----------------
__global__ void k_scale(float* __restrict__ ws) {
    const float* energy = ws + OFF_ENERGY;
    float* scale = ws + OFF_SCALE;
    int b = blockIdx.x;            // 16*289
    int m = b / NSHIFT, s = b % NSHIFT;
    int i = s / SHD, j = s % SHD;
    int y0 = max(0, i - 8), y1 = min(HH, i + 56);
    int x0 = max(0, j - 8), x1 = min(WW, j + 56);
    int ny = y1 - y0, nx = x1 - x0, tot = ny * nx;
    float acc = 0.f;
    for (int idx = threadIdx.x; idx < tot; idx += blockDim.x) {
        int yy = y0 + idx / nx, xx = x0 + idx % nx;
        acc += energy[(m * HH + yy) * WW + xx];
    }
    #pragma unroll
    for (int off = 32; off; off >>= 1) acc += __shfl_xor(acc, off);
    __shared__ float red[4];
    int lane = threadIdx.x & 63, wv = threadIdx.x >> 6;
    if (lane == 0) red[wv] = acc;
    __syncthreads();
    if (threadIdx.x == 0) {
        float tsum = red[0] + red[1] + red[2] + red[3];
        scale[b] = 1.f / fmaxf(sqrtf(tsum), 1e-12f);
    }
}

// ---------------- K3: MFMA cross-correlation ----------------
// grid: 17 dy * 16 h-chunks * 4 c-slices = 1088 blocks, 256 threads (4 waves)
// wave wv owns w in [wv*16, wv*16+16); block stages sat row hs (64 KB) in LDS.
__global__ __launch_bounds__(256, 2) void k_corr(const unsigned short* __restrict__ satb,
                                                 const unsigned short* __restrict__ grdb,
                                                 float* __restrict__ ws) {
    __shared__ alignas(16) unsigned char smem[65536];
    int b = blockIdx.x;
    int dyi = b % 17;
    int hc  = (b / 17) & 15;
    int c0  = (b / (17 * 16)) * 32;
    int t = threadIdx.x;
    int wv = t >> 6, l = t & 63;
    int m16 = l & 15, q = l >> 4;

    floatx4 acc[17];
    #pragma unroll
    for (int d = 0; d < 17; ++d) acc[d] = (floatx4)0.f;

    const unsigned char* aptr = smem + l * 16;
    int wbase = wv * 16;

    for (int hh = 0; hh < 4; ++hh) {
        int h = hc * 4 + hh;
        int hs = h + dyi - 8;
        if ((unsigned)hs >= (unsigned)HH) continue;   // block-uniform

        // stage sat row hs: wave wv stages wp in [wv*16, wv*16+16)
        #pragma unroll
        for (int i = 0; i < 16; ++i) {
            int wp = wbase + i;
            const unsigned short* g = satb + (((size_t)(hs * 64 + wp) * 16 + m16) * 128 + c0 + q * 8);
            __builtin_amdgcn_global_load_lds((AS1 void*)(unsigned short*)g,
                                             (AS3 void*)(smem + wp * 1024), 16, 0, 0);
        }
        __syncthreads();

        bf16x8 B = *(const bf16x8*)(grdb + (((size_t)(h * 64 + wbase) * 16 + m16) * 128 + c0 + q * 8));
        for (int wi = 0; wi < 16; ++wi) {
            int w = wbase + wi;
            int wn = (w + 1 < 64) ? (w + 1) : 63;
            bf16x8 Bn = *(const bf16x8*)(grdb + (((size_t)(h * 64 + wn) * 16 + m16) * 128 + c0 + q * 8));
            #pragma unroll
            for (int dxi = 0; dxi < 17; ++dxi) {
                int wsp = w + dxi - 8;
                if ((unsigned)wsp < (unsigned)WW) {   // wave-uniform
                    bf16x8 A = *(const bf16x8*)(aptr + wsp * 1024);
                    acc[dxi] = __builtin_amdgcn_mfma_f32_16x16x32_bf16(A, B, acc[dxi], 0, 0, 0);
                }
            }
            B = Bn;
        }
        __syncthreads();
    }

    // cross-wave reduce in LDS, then atomics (wave 0 commits)
    __syncthreads();
    if (wv > 0) {
        #pragma unroll
        for (int dxi = 0; dxi < 17; ++dxi)
            *(floatx4*)(smem + (((wv - 1) * 17 + dxi) * 64 + l) * 16) = acc[dxi];
    }
    __syncthreads();
    if (wv == 0) {
        float* raw = ws + OFF_RAW;
        #pragma unroll
        for (int dxi = 0; dxi < 17; ++dxi) {
            floatx4 v = acc[dxi];
            #pragma unroll
            for (int p = 0; p < 3; ++p)
                v += *(floatx4*)(smem + ((p * 17 + dxi) * 64 + l) * 16);
            int s = dyi * 17 + dxi;
            #pragma unroll
            for (int r = 0; r < 4; ++r) {
                int m = q * 4 + r;
                atomicAdd(&raw[(size_t)(m * 16 + m16) * NSHIFT + s], v[r]);
            }
        }
    }
}

// ---------------- K4: epilogue -> 3 scalars ----------------
__global__ void k_final(const float* __restrict__ ws, float* __restrict__ out) {
    const float* raw   = ws + OFF_RAW;
    const float* scale = ws + OFF_SCALE;
    const float* norms = ws + OFF_NORM;
    __shared__ float dist_s[256];
    __shared__ float pos_s[16];
    __shared__ float red[256];
    __shared__ float minv[16];
    int t = threadIdx.x;          // t = m*16 + n
    int m = t >> 4, n = t & 15;

    float best = -1e30f;
    const float* rp = raw + (size_t)t * NSHIFT;
    const float* sp = scale + m * NSHIFT;
    for (int s = 0; s < NSHIFT; ++s) best = fmaxf(best, rp[s] * sp[s]);
    float Ng  = sqrtf(norms[n]);
    float sim = best / fmaxf(Ng, 1e-12f);
    float d   = 2.f - 2.f * sim;
    dist_s[t] = d;
    if (m == n) pos_s[m] = d;
    __syncthreads();

    float x1 = (pos_s[n] - d) * 10.f;
    float x2 = (pos_s[m] - d) * 10.f;
    float sp1 = x1 > 20.f ? x1 : log1pf(expf(x1));
    float sp2 = x2 > 20.f ? x2 : log1pf(expf(x2));
    red[t] = sp1 + sp2;
    __syncthreads();
    for (int off = 128; off; off >>= 1) {
        if (t < off) red[t] += red[t + off];
        __syncthreads();
    }
    if (t < 16) {
        float mv = 1e30f;
        for (int nn = 0; nn < 16; ++nn) mv = fminf(mv, dist_s[t * 16 + nn]);
        minv[t] = mv;
    }
    __syncthreads();
    if (t == 0) {
        float psum = 0.f, msum = 0.f;
        for (int qq = 0; qq < 16; ++qq) { psum += pos_s[qq]; msum += minv[qq]; }
        out[0] = red[0] / 48.f;
        out[1] = psum / 16.f;
        out[2] = msum / 16.f;
    }
}

extern "C" void kernel_launch(void* const* d_in, const int* in_sizes, int n_in,
                              void* d_out, int out_size, void* d_ws, size_t ws_size,
                              hipStream_t stream) {
    const float* sat = (const float*)d_in[0];
    const float* grd = (const float*)d_in[1];
    float* out = (float*)d_out;
    float* ws  = (float*)d_ws;
    const unsigned short* satb = (const unsigned short*)((char*)d_ws + OFF_SATB_B);
    const unsigned short* grdb = satb + TENSOR_U16;

    hipMemsetAsync(d_ws, 0, ZERO_BYTES, stream);
    k_prep <<<2048,          256, 0, stream>>>(sat, grd, ws);
    k_scale<<<16 * NSHIFT,   256, 0, stream>>>(ws);
    k_corr <<<17 * 16 * 4,   256, 0, stream>>>(satb, grdb, ws);
    k_final<<<1,             256, 0, stream>>>(ws, out);
}